// Round 10
// baseline (377.833 us; speedup 1.0000x reference)
//
#include <hip/hip_runtime.h>
#include <stdint.h>

#define SEQ   2048
#define HID   4096
#define NQH   32
#define NKVH  8
#define HD    128
#define QKVN  6144   // (32 + 2*8) * 128

typedef uint16_t u16;
typedef __attribute__((ext_vector_type(8))) short bf16x8;
typedef __attribute__((ext_vector_type(4))) float f32x4;
typedef __attribute__((ext_vector_type(4))) unsigned int u32x4;

static __device__ __forceinline__ float bf2f(u16 h){
  union { float f; unsigned int u; } v; v.u = ((unsigned int)h) << 16; return v.f;
}
static __device__ __forceinline__ u16 f2bf(float f){
  unsigned int u = __float_as_uint(f);
  return (u16)((u + 0x7fffu + ((u >> 16) & 1u)) >> 16);  // RNE, finite inputs only
}
static __device__ __forceinline__ f32x4 mfma16(bf16x8 a, bf16x8 b, f32x4 c){
  return __builtin_amdgcn_mfma_f32_16x16x32_bf16(a, b, c, 0, 0, 0);
}
static __device__ __forceinline__ void gload16(const void* g, void* l){
  __builtin_amdgcn_global_load_lds((const __attribute__((address_space(1))) void*)g,
                                   (__attribute__((address_space(3))) void*)l, 16, 0, 0);
}

// ---------------- fp32 -> bf16 elementwise (n4 = n/4) ----------------
__global__ void k_cvt(const float* __restrict__ src, u16* __restrict__ dst, int n4){
  int i = blockIdx.x * blockDim.x + threadIdx.x;
  if (i >= n4) return;
  float4 v = ((const float4*)src)[i];
  uint2 o;
  o.x = (unsigned)f2bf(v.x) | ((unsigned)f2bf(v.y) << 16);
  o.y = (unsigned)f2bf(v.z) | ((unsigned)f2bf(v.w) << 16);
  ((uint2*)dst)[i] = o;
}

// ---------------- o += a (fp32, n4 = n/4) ----------------
__global__ void k_addf(const float* __restrict__ a, float* __restrict__ o, int n4){
  int i = blockIdx.x * blockDim.x + threadIdx.x;
  if (i >= n4) return;
  float4 x = ((const float4*)o)[i];
  float4 y = ((const float4*)a)[i];
  x.x += y.x; x.y += y.y; x.z += y.z; x.w += y.w;
  ((float4*)o)[i] = x;
}

// ---------------- src[K][N] fp32 -> dst[N][K] bf16 (transpose-convert) ----------------
__global__ void k_transpose_cvt(const float* __restrict__ src, u16* __restrict__ dst, int K, int N){
  __shared__ float t[32][33];
  int n0 = blockIdx.x * 32, k0 = blockIdx.y * 32;
  int tx = threadIdx.x, ty = threadIdx.y;
#pragma unroll
  for (int i = 0; i < 32; i += 8)
    t[ty + i][tx] = src[(size_t)(k0 + ty + i) * N + n0 + tx];
  __syncthreads();
#pragma unroll
  for (int i = 0; i < 32; i += 8)
    dst[(size_t)(n0 + ty + i) * K + k0 + tx] = f2bf(t[tx][ty + i]);
}

// ---------------- C[M][N] = A[M][K] @ Bt[N][K]^T, bf16 in, OUTBF? bf16 : fp32 out ----------------
// r5 structure (verified best): BM=BN=256, BK=64, 512 thr / 8 waves (2M x 4N),
// wave tile 128x64, 4 phases of 16-MFMA clusters, LDS 128 KB double-buffer,
// tile t+1's 8 gloads issued in phases 0-1 (full-tile slack).
// 1D grid + bijective XCD block mapping (kept from r9: neutral, harmless).
// Granule XOR swizzle g^=(row&7) both sides (measured: 0 bank conflicts).
template<int OUTBF, int SPLITK, int XBC, int NBY>
__global__ __launch_bounds__(512) void k_gemm(const u16* __restrict__ A, const u16* __restrict__ Bt,
                                              void* __restrict__ Cv0, void* __restrict__ Cv1,
                                              int M, int N, int K){
  __shared__ __align__(16) u16 Asm[2][256][64];   // 64 KB
  __shared__ __align__(16) u16 Bsm[2][256][64];   // 64 KB
  const int tid = threadIdx.x, lane = tid & 63, wid = tid >> 6;
  const int wm = wid >> 2, wn = wid & 3;          // 2 x 4 wave grid
  const int l16 = lane & 15, lhi = lane >> 4;
  const int rx = l16 & 7;                          // read-side swizzle key (= row&7)
  // XCD-locality block mapping (bijective): bid -> (bcol, brow, kz)
  const int bid = blockIdx.x;
  const int xcd = bid & 7, j = bid >> 3;
  const int bcol_i = xcd * XBC + j % XBC;
  const int rest = j / XBC;
  const int brow_i = rest % NBY;
  const int kz = (SPLITK > 1) ? (rest / NBY) : 0;
  const size_t brow = (size_t)brow_i * 256, bcol = (size_t)bcol_i * 256;
  const int kbeg = kz * (K / SPLITK);
  void* Cv = (kz == 0) ? Cv0 : Cv1;

  const f32x4 vz = {0.f, 0.f, 0.f, 0.f};
  f32x4 acc[8][4];
#pragma unroll
  for (int m = 0; m < 8; m++)
#pragma unroll
    for (int n = 0; n < 4; n++) acc[m][n] = vz;

  // staging: 4 gloads per matrix per wave per K-tile; gload j covers rows wid*8 + j*64 .. +7
  const int srow = lane >> 3;                      // row within 8-row group
  const int sg   = (lane & 7) ^ srow;              // pre-swizzled source granule
  const u16* Ags = A  + (brow + wid*8 + srow) * (size_t)K + sg*8 + kbeg;
  const u16* Bgs = Bt + (bcol + wid*8 + srow) * (size_t)K + sg*8 + kbeg;
  const int NT = (K / SPLITK) >> 6;

  // prologue: stage tile 0 -> buf 0
#pragma unroll
  for (int j2 = 0; j2 < 4; j2++) gload16(Ags + (size_t)j2*64*K, &Asm[0][wid*8 + j2*64][0]);
#pragma unroll
  for (int j2 = 0; j2 < 4; j2++) gload16(Bgs + (size_t)j2*64*K, &Bsm[0][wid*8 + j2*64][0]);
  asm volatile("s_waitcnt vmcnt(0)" ::: "memory");
  __builtin_amdgcn_sched_barrier(0);
  __builtin_amdgcn_s_barrier();

  for (int t = 0; t < NT; ++t){
    const int cur = t & 1, nxt = cur ^ 1;
    const size_t ko = (size_t)(t + 1) * 64;
    const bool st = (t + 1 < NT);
    bf16x8 a[8], b0, b1, b2, b3;
    // ---------- phase 0: A(kh0) x8 + B ni0,ni1(kh0); stage A0,A1,B0,B1 of t+1 ----------
#pragma unroll
    for (int mi = 0; mi < 8; ++mi)
      a[mi] = *(const bf16x8*)&Asm[cur][wm*128 + mi*16 + l16][(lhi ^ rx) << 3];
    b0 = *(const bf16x8*)&Bsm[cur][wn*64 +  0 + l16][(lhi ^ rx) << 3];
    b1 = *(const bf16x8*)&Bsm[cur][wn*64 + 16 + l16][(lhi ^ rx) << 3];
    if (st){
      gload16(Ags + ko,                  &Asm[nxt][wid*8      ][0]);
      gload16(Ags + (size_t)64*K + ko,   &Asm[nxt][wid*8 +  64][0]);
      gload16(Bgs + ko,                  &Bsm[nxt][wid*8      ][0]);
      gload16(Bgs + (size_t)64*K + ko,   &Bsm[nxt][wid*8 +  64][0]);
    }
    __builtin_amdgcn_s_barrier();
    asm volatile("s_waitcnt lgkmcnt(0)" ::: "memory");
    __builtin_amdgcn_sched_barrier(0);
    __builtin_amdgcn_s_setprio(1);
#pragma unroll
    for (int mi = 0; mi < 8; ++mi){
      acc[mi][0] = mfma16(a[mi], b0, acc[mi][0]);
      acc[mi][1] = mfma16(a[mi], b1, acc[mi][1]);
    }
    __builtin_amdgcn_s_setprio(0);
    __builtin_amdgcn_s_barrier();
    // ---------- phase 1: B ni2,ni3(kh0); stage A2,A3,B2,B3 of t+1 ----------
    b2 = *(const bf16x8*)&Bsm[cur][wn*64 + 32 + l16][(lhi ^ rx) << 3];
    b3 = *(const bf16x8*)&Bsm[cur][wn*64 + 48 + l16][(lhi ^ rx) << 3];
    if (st){
      gload16(Ags + (size_t)128*K + ko,  &Asm[nxt][wid*8 + 128][0]);
      gload16(Ags + (size_t)192*K + ko,  &Asm[nxt][wid*8 + 192][0]);
      gload16(Bgs + (size_t)128*K + ko,  &Bsm[nxt][wid*8 + 128][0]);
      gload16(Bgs + (size_t)192*K + ko,  &Bsm[nxt][wid*8 + 192][0]);
    }
    __builtin_amdgcn_s_barrier();
    asm volatile("s_waitcnt lgkmcnt(0)" ::: "memory");
    __builtin_amdgcn_sched_barrier(0);
    __builtin_amdgcn_s_setprio(1);
#pragma unroll
    for (int mi = 0; mi < 8; ++mi){
      acc[mi][2] = mfma16(a[mi], b2, acc[mi][2]);
      acc[mi][3] = mfma16(a[mi], b3, acc[mi][3]);
    }
    __builtin_amdgcn_s_setprio(0);
    __builtin_amdgcn_s_barrier();
    // ---------- phase 2: A(kh1) x8 + B ni0,ni1(kh1) ----------
#pragma unroll
    for (int mi = 0; mi < 8; ++mi)
      a[mi] = *(const bf16x8*)&Asm[cur][wm*128 + mi*16 + l16][((4 + lhi) ^ rx) << 3];
    b0 = *(const bf16x8*)&Bsm[cur][wn*64 +  0 + l16][((4 + lhi) ^ rx) << 3];
    b1 = *(const bf16x8*)&Bsm[cur][wn*64 + 16 + l16][((4 + lhi) ^ rx) << 3];
    __builtin_amdgcn_s_barrier();
    asm volatile("s_waitcnt lgkmcnt(0)" ::: "memory");
    __builtin_amdgcn_sched_barrier(0);
    __builtin_amdgcn_s_setprio(1);
#pragma unroll
    for (int mi = 0; mi < 8; ++mi){
      acc[mi][0] = mfma16(a[mi], b0, acc[mi][0]);
      acc[mi][1] = mfma16(a[mi], b1, acc[mi][1]);
    }
    __builtin_amdgcn_s_setprio(0);
    __builtin_amdgcn_s_barrier();
    // ---------- phase 3: B ni2,ni3(kh1); end-of-tile vmcnt drain (pre-satisfied) ----------
    b2 = *(const bf16x8*)&Bsm[cur][wn*64 + 32 + l16][((4 + lhi) ^ rx) << 3];
    b3 = *(const bf16x8*)&Bsm[cur][wn*64 + 48 + l16][((4 + lhi) ^ rx) << 3];
    __builtin_amdgcn_s_barrier();
    asm volatile("s_waitcnt lgkmcnt(0)" ::: "memory");
    __builtin_amdgcn_sched_barrier(0);
    __builtin_amdgcn_s_setprio(1);
#pragma unroll
    for (int mi = 0; mi < 8; ++mi){
      acc[mi][2] = mfma16(a[mi], b2, acc[mi][2]);
      acc[mi][3] = mfma16(a[mi], b3, acc[mi][3]);
    }
    __builtin_amdgcn_s_setprio(0);
    if (st){
      asm volatile("s_waitcnt vmcnt(0)" ::: "memory");  // tile t+1 landed (issued ~3 phases ago)
      __builtin_amdgcn_sched_barrier(0);
    }
    __builtin_amdgcn_s_barrier();
  }

  // epilogue: C/D layout col=l16, row=lhi*4+i
#pragma unroll
  for (int mi = 0; mi < 8; mi++)
#pragma unroll
    for (int ni = 0; ni < 4; ni++)
#pragma unroll
      for (int i = 0; i < 4; i++){
        size_t row = brow + wm*128 + mi*16 + lhi*4 + i;
        size_t col = bcol + wn*64 + ni*16 + l16;
        if (OUTBF) ((u16*)Cv)[row * (size_t)N + col] = f2bf(acc[mi][ni][i]);
        else       ((float*)Cv)[row * (size_t)N + col] = acc[mi][ni][i];
      }
}

// ---------------- RMSNorm + RoPE: qkv bf16 -> Q[h][t][d], K[h][t][d] (scale folded into Q) ----------------
__global__ __launch_bounds__(256) void k_rmsrope(const u16* __restrict__ qkv, const float* __restrict__ cosp,
                                                 const float* __restrict__ sinp, const float* __restrict__ qw,
                                                 const float* __restrict__ kw, u16* __restrict__ Qr,
                                                 u16* __restrict__ Kr){
  int t = blockIdx.x;
  int lane = threadIdx.x & 63, w = threadIdx.x >> 6;
  int hh = blockIdx.y * 4 + w;          // 0..39: 32 q heads + 8 k heads
  bool isq = hh < NQH;
  int hl = isq ? hh : hh - NQH;
  const u16* src = qkv + (size_t)t * QKVN + (isq ? hl * HD : NQH * HD + hl * HD);
  unsigned u = *(const unsigned*)(src + 2 * lane);       // d = 2*lane, 2*lane+1
  float x0 = bf2f((u16)(u & 0xffffu)), x1 = bf2f((u16)(u >> 16));
  float ss = x0 * x0 + x1 * x1;
#pragma unroll
  for (int m = 1; m < 64; m <<= 1) ss += __shfl_xor(ss, m);
  float rs = rsqrtf(ss * (1.f / HD) + 1e-6f);
  const float* wp = isq ? qw : kw;
  float w0 = wp[2 * lane], w1 = wp[2 * lane + 1];
  float xn0 = x0 * rs * w0, xn1 = x1 * rs * w1;
  float p0 = __shfl_xor(xn0, 32), p1 = __shfl_xor(xn1, 32);  // rotate-half partner
  int j0 = (2 * lane) & 63;
  float c0 = cosp[t * 64 + j0], c1 = cosp[t * 64 + j0 + 1];
  float s0 = sinp[t * 64 + j0], s1 = sinp[t * 64 + j0 + 1];
  float o0, o1;
  if (lane < 32){ o0 = xn0 * c0 - p0 * s0; o1 = xn1 * c1 - p1 * s1; }
  else          { o0 = xn0 * c0 + p0 * s0; o1 = xn1 * c1 + p1 * s1; }
  if (isq){ o0 *= 0.08838834764831845f; o1 *= 0.08838834764831845f; }  // D^-0.5
  u16* dst = isq ? (Qr + ((size_t)hl * SEQ + t) * HD) : (Kr + ((size_t)hl * SEQ + t) * HD);
  *(unsigned*)(dst + 2 * lane) = (unsigned)f2bf(o0) | ((unsigned)f2bf(o1) << 16);
}

// ---------------- V slice of qkv -> VT[h][d][t] bf16 ----------------
__global__ void k_vt(const u16* __restrict__ qkv, u16* __restrict__ VT){
  __shared__ u16 t[32][33];
  int t0 = blockIdx.x * 32, d0 = blockIdx.y * 32, hv = blockIdx.z;
  int tx = threadIdx.x, ty = threadIdx.y;
#pragma unroll
  for (int i = 0; i < 32; i += 8)
    t[ty + i][tx] = qkv[(size_t)(t0 + ty + i) * QKVN + (NQH + NKVH) * HD + hv * HD + d0 + tx];
  __syncthreads();
#pragma unroll
  for (int i = 0; i < 32; i += 8)
    VT[((size_t)hv * HD + d0 + ty + i) * SEQ + t0 + tx] = t[tx][ty + i];
}

// ---------------- causal GQA flash attention ----------------
// 512 blocks (8 waves, 512 thr): one 128-row q-tile per block, longest-first.
// bid -> kvg=bid&7 (XCD L2 locality), J=15-(rr>>2) desc.
// LDS = 80 KB EXACTLY -> 2 blocks/CU (the round-10 lever: co-resident block's MFMA
// hides the other's softmax/staging latency; was 84 KB -> 1 block/CU).
// Psm stride 72 -> 64 with granule XOR swizzle (write g=(col>>3)^(q&3), read
// g=(ksv*4+lhi)^(l16&3) -- same involution; 4-way conflict on 2/36 LDS ops, free-ish).
// K/V double-buffered via global_load_lds, G21 swizzle; 1 barrier per KV tile.
__global__ __launch_bounds__(512, 4) void k_attn(const u16* __restrict__ Q, const u16* __restrict__ Kg,
                                                 const u16* __restrict__ VTg, u16* __restrict__ AO){
  __shared__ __align__(16) u16 Ksm[2][64][128];   // 32 KB [buf][kv][d], 16B-granule swizzled
  __shared__ __align__(16) u16 Vsm[2][128][64];   // 32 KB [buf][d][kv], swizzled
  __shared__ __align__(16) u16 Psm[8][16][64];    // 16 KB per-wave P [q][kv], granule-swizzled
  int tid = threadIdx.x, lane = tid & 63, wid = tid >> 6;
  int l16 = lane & 15, lhi = lane >> 4;
  int bid = blockIdx.x;
  int kvg = bid & 7, rr = bid >> 3;               // 64 blocks per kv-group
  int J = 15 - (rr >> 2);                         // longest-first
  int hq = kvg * 4 + (rr & 3);
  int qb = J * 128;
  const u16* Kh = Kg  + (size_t)kvg * SEQ * HD;
  const u16* Vh = VTg + (size_t)kvg * HD * SEQ;
  const u16* Qh = Q   + (size_t)hq * SEQ * HD;

  // Q fragments: wave owns rows qb + wid*16 .. +15
  bf16x8 qf[4];
#pragma unroll
  for (int ks = 0; ks < 4; ks++)
    qf[ks] = *(const bf16x8*)(Qh + (size_t)(qb + wid*16 + l16) * HD + ks*32 + lhi*8);

  const f32x4 vz = {0.f, 0.f, 0.f, 0.f};
  f32x4 o[8];
  float mrow[4], lrow[4];
#pragma unroll
  for (int n = 0; n < 8; n++) o[n] = vz;
#pragma unroll
  for (int i = 0; i < 4; i++){ mrow[i] = -1e30f; lrow[i] = 0.f; }

  // staging source pointers (pre-swizzled so linear LDS + swizzled read = identity)
  int krl0 = wid*8 + (lane >> 4), krl1 = krl0 + 4;          // K rows (8/wave, 2 issues)
  int kgs  = lane & 15;
  const u16* ks0 = Kh + (size_t)krl0 * HD + ((kgs ^ (krl0 & 7)) << 3);
  const u16* ks1 = Kh + (size_t)krl1 * HD + ((kgs ^ (krl1 & 7)) << 3);
  int vrl0 = wid*16 + (lane >> 3), vrl1 = vrl0 + 8;         // V d-rows (16/wave, 2 issues)
  int vgs  = lane & 7;
  const u16* vs0 = Vh + (size_t)vrl0 * SEQ + ((vgs ^ (vrl0 & 7)) << 3);
  const u16* vs1 = Vh + (size_t)vrl1 * SEQ + ((vgs ^ (vrl1 & 7)) << 3);

  // prologue: stage tile 0 into buffer 0
  gload16(ks0, &Ksm[0][wid*8][0]);
  gload16(ks1, &Ksm[0][wid*8 + 4][0]);
  gload16(vs0, &Vsm[0][wid*16][0]);
  gload16(vs1, &Vsm[0][wid*16 + 8][0]);
  __syncthreads();

  int ntr = 2*J + 2;
  int wrow0 = qb + wid*16;
  for (int t = 0; t < ntr; t++){
    int cur = t & 1, nxt = cur ^ 1;
    int kt0 = t << 6;
    if (t < ntr - 1){  // async prefetch tile t+1 (overlaps whole trip; drained at barrier)
      size_t ko = (size_t)(t + 1) * 64 * HD;
      gload16(ks0 + ko, &Ksm[nxt][wid*8][0]);
      gload16(ks1 + ko, &Ksm[nxt][wid*8 + 4][0]);
      int vo = (t + 1) * 64;
      gload16(vs0 + vo, &Vsm[nxt][wid*16][0]);
      gload16(vs1 + vo, &Vsm[nxt][wid*16 + 8][0]);
    }
    if (kt0 <= wrow0 + 15){   // wave has unmasked rows in this tile
      // QK^T from swizzled Ksm
      f32x4 s[4];
#pragma unroll
      for (int n = 0; n < 4; n++) s[n] = vz;
      const u16* kbase = &Ksm[cur][0][0];
#pragma unroll
      for (int n = 0; n < 4; n++){
        int row = n*16 + l16, rxk = row & 7;
#pragma unroll
        for (int ks = 0; ks < 4; ks++){
          bf16x8 kf = *(const bf16x8*)(kbase + row*128 + (((ks*4 + lhi) ^ rxk) << 3));
          s[n] = mfma16(qf[ks], kf, s[n]);
        }
      }
      // causal mask (diagonal region only)
      if (kt0 + 63 > wrow0){
#pragma unroll
        for (int n = 0; n < 4; n++)
#pragma unroll
          for (int i = 0; i < 4; i++)
            if (kt0 + n*16 + l16 > wrow0 + lhi*4 + i) s[n][i] = -1e30f;
      }
      // online softmax (row q lives in 16 lanes sharing lhi*4+i)
#pragma unroll
      for (int i = 0; i < 4; i++){
        float tm = fmaxf(fmaxf(s[0][i], s[1][i]), fmaxf(s[2][i], s[3][i]));
        tm = fmaxf(tm, __shfl_xor(tm, 1));
        tm = fmaxf(tm, __shfl_xor(tm, 2));
        tm = fmaxf(tm, __shfl_xor(tm, 4));
        tm = fmaxf(tm, __shfl_xor(tm, 8));
        float nm = fmaxf(mrow[i], tm);
        float sc = __expf(mrow[i] - nm);
        mrow[i] = nm;
        float rsum = 0.f;
#pragma unroll
        for (int n = 0; n < 4; n++){
          float p = __expf(s[n][i] - nm);
          s[n][i] = p;
          rsum += p;
        }
        rsum += __shfl_xor(rsum, 1);
        rsum += __shfl_xor(rsum, 2);
        rsum += __shfl_xor(rsum, 4);
        rsum += __shfl_xor(rsum, 8);
        lrow[i] = lrow[i] * sc + rsum;
#pragma unroll
        for (int n = 0; n < 8; n++) o[n][i] *= sc;
      }
      // P (D-layout) -> per-wave LDS, granule-swizzled (no barrier: same-wave prod/cons)
#pragma unroll
      for (int n = 0; n < 4; n++)
#pragma unroll
        for (int i = 0; i < 4; i++){
          int q = lhi*4 + i, col = n*16 + l16;
          int pcol = ((((col >> 3) ^ (q & 3)) << 3) | (col & 7));
          Psm[wid][q][pcol] = f2bf(s[n][i]);
        }
      // PV from swizzled Vsm; P A-frags from swizzled Psm
      const u16* vbase = &Vsm[cur][0][0];
#pragma unroll
      for (int ksv = 0; ksv < 2; ksv++){
        bf16x8 pa = *(const bf16x8*)&Psm[wid][l16][(((ksv*4 + lhi) ^ (l16 & 3)) << 3)];
#pragma unroll
        for (int n = 0; n < 8; n++){
          int row = n*16 + l16;
          bf16x8 vb = *(const bf16x8*)(vbase + row*64 + ((((ksv*4) + lhi) ^ (row & 7)) << 3));
          o[n] = mfma16(pa, vb, o[n]);
        }
      }
    }
    if (t < ntr - 1) __syncthreads();  // drains prefetch (vmcnt0) + swaps buffers
  }
  // epilogue: O /= l, write bf16 to AO[t][hq*128 + d]
  float inv[4];
#pragma unroll
  for (int i = 0; i < 4; i++) inv[i] = 1.f / lrow[i];
#pragma unroll
  for (int n = 0; n < 8; n++)
#pragma unroll
    for (int i = 0; i < 4; i++){
      int trow = wrow0 + lhi*4 + i;
      AO[(size_t)trow * HID + hq * HD + n*16 + l16] = f2bf(o[n][i] * inv[i]);
    }
}

// ---------------- launch ----------------
extern "C" void kernel_launch(void* const* d_in, const int* in_sizes, int n_in,
                              void* d_out, int out_size, void* d_ws, size_t ws_size,
                              hipStream_t stream){
  const float* hs   = (const float*)d_in[0];
  const float* cosp = (const float*)d_in[1];
  const float* sinp = (const float*)d_in[2];
  const float* wqkv = (const float*)d_in[3];
  const float* wo   = (const float*)d_in[4];
  const float* qw   = (const float*)d_in[5];
  const float* kw   = (const float*)d_in[6];
  float* out = (float*)d_out;
  char* ws = (char*)d_ws;
  // workspace layout (128 MB total); WOT reuses XB region after GEMM1; SCR (split-K
  // fp32 partial, 33.55 MB) reuses [33.5M, 67.1M) = rest of WQKVT region, dead after GEMM1.
  u16* XB    = (u16*)(ws + 0);            // 16.8 MB  X bf16 [2048][4096]
  u16* WQKVT = (u16*)(ws + 16777216);     // 50.3 MB  WqkvT bf16 [6144][4096]
  u16* WOT   = (u16*)(ws + 0);            // 33.6 MB  WoT bf16 [4096][4096] (after GEMM1)
  float* SCR = (float*)(ws + 33554432);   // 33.6 MB  fp32 partial [2048][4096]
  u16* QKV   = (u16*)(ws + 67108864);     // 25.2 MB  qkv bf16 [2048][6144]
  u16* QR    = (u16*)(ws + 92274688);     // 16.8 MB  Q bf16 [32][2048][128]
  u16* KR    = (u16*)(ws + 109051904);    //  4.2 MB  K bf16 [8][2048][128]
  u16* VTB   = (u16*)(ws + 113246208);    //  4.2 MB  VT bf16 [8][128][2048]
  u16* AOB   = (u16*)(ws + 117440512);    // 16.8 MB  attn out bf16 [2048][4096]

  k_cvt<<<(SEQ * HID / 4 + 255) / 256, 256, 0, stream>>>(hs, XB, SEQ * HID / 4);
  k_transpose_cvt<<<dim3(QKVN / 32, HID / 32), dim3(32, 8), 0, stream>>>(wqkv, WQKVT, HID, QKVN);
  // GEMM1: 192 blocks = 8 XCD x (3 bcol x 8 brow)
  k_gemm<1, 1, 3, 8><<<192, 512, 0, stream>>>(XB, WQKVT, QKV, nullptr, SEQ, QKVN, HID);
  k_transpose_cvt<<<dim3(HID / 32, HID / 32), dim3(32, 8), 0, stream>>>(wo, WOT, HID, HID);
  k_rmsrope<<<dim3(SEQ, 10), 256, 0, stream>>>(QKV, cosp, sinp, qw, kw, QR, KR);
  k_vt<<<dim3(SEQ / 32, HD / 32, NKVH), dim3(32, 8), 0, stream>>>(QKV, VTB);
  k_attn<<<512, 512, 0, stream>>>(QR, KR, VTB, AOB);
  // GEMM2: 256 blocks = 8 XCD x (2 bcol x 8 brow x 2 kz), split-K=2
  k_gemm<0, 2, 2, 8><<<256, 512, 0, stream>>>(AOB, WOT, out, SCR, SEQ, HID, HID);
  k_addf<<<SEQ * HID / 4 / 256, 256, 0, stream>>>(SCR, out, SEQ * HID / 4);
}

// Round 11
// 358.316 us; speedup vs baseline: 1.0545x; 1.0545x over previous
//
#include <hip/hip_runtime.h>
#include <stdint.h>

#define SEQ   2048
#define HID   4096
#define NQH   32
#define NKVH  8
#define HD    128
#define QKVN  6144   // (32 + 2*8) * 128

typedef uint16_t u16;
typedef __attribute__((ext_vector_type(8))) short bf16x8;
typedef __attribute__((ext_vector_type(4))) float f32x4;
typedef __attribute__((ext_vector_type(4))) unsigned int u32x4;

static __device__ __forceinline__ float bf2f(u16 h){
  union { float f; unsigned int u; } v; v.u = ((unsigned int)h) << 16; return v.f;
}
static __device__ __forceinline__ u16 f2bf(float f){
  unsigned int u = __float_as_uint(f);
  return (u16)((u + 0x7fffu + ((u >> 16) & 1u)) >> 16);  // RNE, finite inputs only
}
static __device__ __forceinline__ f32x4 mfma16(bf16x8 a, bf16x8 b, f32x4 c){
  return __builtin_amdgcn_mfma_f32_16x16x32_bf16(a, b, c, 0, 0, 0);
}
static __device__ __forceinline__ void gload16(const void* g, void* l){
  __builtin_amdgcn_global_load_lds((const __attribute__((address_space(1))) void*)g,
                                   (__attribute__((address_space(3))) void*)l, 16, 0, 0);
}

// ---------------- fp32 -> bf16 elementwise (n4 = n/4) ----------------
__global__ void k_cvt(const float* __restrict__ src, u16* __restrict__ dst, int n4){
  int i = blockIdx.x * blockDim.x + threadIdx.x;
  if (i >= n4) return;
  float4 v = ((const float4*)src)[i];
  uint2 o;
  o.x = (unsigned)f2bf(v.x) | ((unsigned)f2bf(v.y) << 16);
  o.y = (unsigned)f2bf(v.z) | ((unsigned)f2bf(v.w) << 16);
  ((uint2*)dst)[i] = o;
}

// ---------------- o += a (fp32, n4 = n/4) ----------------
__global__ void k_addf(const float* __restrict__ a, float* __restrict__ o, int n4){
  int i = blockIdx.x * blockDim.x + threadIdx.x;
  if (i >= n4) return;
  float4 x = ((const float4*)o)[i];
  float4 y = ((const float4*)a)[i];
  x.x += y.x; x.y += y.y; x.z += y.z; x.w += y.w;
  ((float4*)o)[i] = x;
}

// ---------------- src[K][N] fp32 -> dst[N][K] bf16 (transpose-convert) ----------------
__global__ void k_transpose_cvt(const float* __restrict__ src, u16* __restrict__ dst, int K, int N){
  __shared__ float t[32][33];
  int n0 = blockIdx.x * 32, k0 = blockIdx.y * 32;
  int tx = threadIdx.x, ty = threadIdx.y;
#pragma unroll
  for (int i = 0; i < 32; i += 8)
    t[ty + i][tx] = src[(size_t)(k0 + ty + i) * N + n0 + tx];
  __syncthreads();
#pragma unroll
  for (int i = 0; i < 32; i += 8)
    dst[(size_t)(n0 + ty + i) * K + k0 + tx] = f2bf(t[tx][ty + i]);
}

// ---------------- C[M][N] = A[M][K] @ Bt[N][K]^T, bf16 in, OUTBF? bf16 : fp32 out ----------------
// r5 structure (verified best): BM=BN=256, BK=64, 512 thr / 8 waves (2M x 4N),
// wave tile 128x64, 4 phases of 16-MFMA clusters, LDS 128 KB double-buffer,
// tile t+1's 8 gloads issued in phases 0-1 (full-tile slack).
// 1D grid + bijective XCD block mapping (neutral, harmless).
// Granule XOR swizzle g^=(row&7) both sides (measured: 0 bank conflicts).
template<int OUTBF, int SPLITK, int XBC, int NBY>
__global__ __launch_bounds__(512) void k_gemm(const u16* __restrict__ A, const u16* __restrict__ Bt,
                                              void* __restrict__ Cv0, void* __restrict__ Cv1,
                                              int M, int N, int K){
  __shared__ __align__(16) u16 Asm[2][256][64];   // 64 KB
  __shared__ __align__(16) u16 Bsm[2][256][64];   // 64 KB
  const int tid = threadIdx.x, lane = tid & 63, wid = tid >> 6;
  const int wm = wid >> 2, wn = wid & 3;          // 2 x 4 wave grid
  const int l16 = lane & 15, lhi = lane >> 4;
  const int rx = l16 & 7;                          // read-side swizzle key (= row&7)
  // XCD-locality block mapping (bijective): bid -> (bcol, brow, kz)
  const int bid = blockIdx.x;
  const int xcd = bid & 7, j = bid >> 3;
  const int bcol_i = xcd * XBC + j % XBC;
  const int rest = j / XBC;
  const int brow_i = rest % NBY;
  const int kz = (SPLITK > 1) ? (rest / NBY) : 0;
  const size_t brow = (size_t)brow_i * 256, bcol = (size_t)bcol_i * 256;
  const int kbeg = kz * (K / SPLITK);
  void* Cv = (kz == 0) ? Cv0 : Cv1;

  const f32x4 vz = {0.f, 0.f, 0.f, 0.f};
  f32x4 acc[8][4];
#pragma unroll
  for (int m = 0; m < 8; m++)
#pragma unroll
    for (int n = 0; n < 4; n++) acc[m][n] = vz;

  // staging: 4 gloads per matrix per wave per K-tile; gload j covers rows wid*8 + j*64 .. +7
  const int srow = lane >> 3;                      // row within 8-row group
  const int sg   = (lane & 7) ^ srow;              // pre-swizzled source granule
  const u16* Ags = A  + (brow + wid*8 + srow) * (size_t)K + sg*8 + kbeg;
  const u16* Bgs = Bt + (bcol + wid*8 + srow) * (size_t)K + sg*8 + kbeg;
  const int NT = (K / SPLITK) >> 6;

  // prologue: stage tile 0 -> buf 0
#pragma unroll
  for (int j2 = 0; j2 < 4; j2++) gload16(Ags + (size_t)j2*64*K, &Asm[0][wid*8 + j2*64][0]);
#pragma unroll
  for (int j2 = 0; j2 < 4; j2++) gload16(Bgs + (size_t)j2*64*K, &Bsm[0][wid*8 + j2*64][0]);
  asm volatile("s_waitcnt vmcnt(0)" ::: "memory");
  __builtin_amdgcn_sched_barrier(0);
  __builtin_amdgcn_s_barrier();

  for (int t = 0; t < NT; ++t){
    const int cur = t & 1, nxt = cur ^ 1;
    const size_t ko = (size_t)(t + 1) * 64;
    const bool st = (t + 1 < NT);
    bf16x8 a[8], b0, b1, b2, b3;
    // ---------- phase 0: A(kh0) x8 + B ni0,ni1(kh0); stage A0,A1,B0,B1 of t+1 ----------
#pragma unroll
    for (int mi = 0; mi < 8; ++mi)
      a[mi] = *(const bf16x8*)&Asm[cur][wm*128 + mi*16 + l16][(lhi ^ rx) << 3];
    b0 = *(const bf16x8*)&Bsm[cur][wn*64 +  0 + l16][(lhi ^ rx) << 3];
    b1 = *(const bf16x8*)&Bsm[cur][wn*64 + 16 + l16][(lhi ^ rx) << 3];
    if (st){
      gload16(Ags + ko,                  &Asm[nxt][wid*8      ][0]);
      gload16(Ags + (size_t)64*K + ko,   &Asm[nxt][wid*8 +  64][0]);
      gload16(Bgs + ko,                  &Bsm[nxt][wid*8      ][0]);
      gload16(Bgs + (size_t)64*K + ko,   &Bsm[nxt][wid*8 +  64][0]);
    }
    __builtin_amdgcn_s_barrier();
    asm volatile("s_waitcnt lgkmcnt(0)" ::: "memory");
    __builtin_amdgcn_sched_barrier(0);
    __builtin_amdgcn_s_setprio(1);
#pragma unroll
    for (int mi = 0; mi < 8; ++mi){
      acc[mi][0] = mfma16(a[mi], b0, acc[mi][0]);
      acc[mi][1] = mfma16(a[mi], b1, acc[mi][1]);
    }
    __builtin_amdgcn_s_setprio(0);
    __builtin_amdgcn_s_barrier();
    // ---------- phase 1: B ni2,ni3(kh0); stage A2,A3,B2,B3 of t+1 ----------
    b2 = *(const bf16x8*)&Bsm[cur][wn*64 + 32 + l16][(lhi ^ rx) << 3];
    b3 = *(const bf16x8*)&Bsm[cur][wn*64 + 48 + l16][(lhi ^ rx) << 3];
    if (st){
      gload16(Ags + (size_t)128*K + ko,  &Asm[nxt][wid*8 + 128][0]);
      gload16(Ags + (size_t)192*K + ko,  &Asm[nxt][wid*8 + 192][0]);
      gload16(Bgs + (size_t)128*K + ko,  &Bsm[nxt][wid*8 + 128][0]);
      gload16(Bgs + (size_t)192*K + ko,  &Bsm[nxt][wid*8 + 192][0]);
    }
    __builtin_amdgcn_s_barrier();
    asm volatile("s_waitcnt lgkmcnt(0)" ::: "memory");
    __builtin_amdgcn_sched_barrier(0);
    __builtin_amdgcn_s_setprio(1);
#pragma unroll
    for (int mi = 0; mi < 8; ++mi){
      acc[mi][2] = mfma16(a[mi], b2, acc[mi][2]);
      acc[mi][3] = mfma16(a[mi], b3, acc[mi][3]);
    }
    __builtin_amdgcn_s_setprio(0);
    __builtin_amdgcn_s_barrier();
    // ---------- phase 2: A(kh1) x8 + B ni0,ni1(kh1) ----------
#pragma unroll
    for (int mi = 0; mi < 8; ++mi)
      a[mi] = *(const bf16x8*)&Asm[cur][wm*128 + mi*16 + l16][((4 + lhi) ^ rx) << 3];
    b0 = *(const bf16x8*)&Bsm[cur][wn*64 +  0 + l16][((4 + lhi) ^ rx) << 3];
    b1 = *(const bf16x8*)&Bsm[cur][wn*64 + 16 + l16][((4 + lhi) ^ rx) << 3];
    __builtin_amdgcn_s_barrier();
    asm volatile("s_waitcnt lgkmcnt(0)" ::: "memory");
    __builtin_amdgcn_sched_barrier(0);
    __builtin_amdgcn_s_setprio(1);
#pragma unroll
    for (int mi = 0; mi < 8; ++mi){
      acc[mi][0] = mfma16(a[mi], b0, acc[mi][0]);
      acc[mi][1] = mfma16(a[mi], b1, acc[mi][1]);
    }
    __builtin_amdgcn_s_setprio(0);
    __builtin_amdgcn_s_barrier();
    // ---------- phase 3: B ni2,ni3(kh1); end-of-tile vmcnt drain (pre-satisfied) ----------
    b2 = *(const bf16x8*)&Bsm[cur][wn*64 + 32 + l16][((4 + lhi) ^ rx) << 3];
    b3 = *(const bf16x8*)&Bsm[cur][wn*64 + 48 + l16][((4 + lhi) ^ rx) << 3];
    __builtin_amdgcn_s_barrier();
    asm volatile("s_waitcnt lgkmcnt(0)" ::: "memory");
    __builtin_amdgcn_sched_barrier(0);
    __builtin_amdgcn_s_setprio(1);
#pragma unroll
    for (int mi = 0; mi < 8; ++mi){
      acc[mi][2] = mfma16(a[mi], b2, acc[mi][2]);
      acc[mi][3] = mfma16(a[mi], b3, acc[mi][3]);
    }
    __builtin_amdgcn_s_setprio(0);
    if (st){
      asm volatile("s_waitcnt vmcnt(0)" ::: "memory");  // tile t+1 landed (issued ~3 phases ago)
      __builtin_amdgcn_sched_barrier(0);
    }
    __builtin_amdgcn_s_barrier();
  }

  // epilogue: C/D layout col=l16, row=lhi*4+i
#pragma unroll
  for (int mi = 0; mi < 8; mi++)
#pragma unroll
    for (int ni = 0; ni < 4; ni++)
#pragma unroll
      for (int i = 0; i < 4; i++){
        size_t row = brow + wm*128 + mi*16 + lhi*4 + i;
        size_t col = bcol + wn*64 + ni*16 + l16;
        if (OUTBF) ((u16*)Cv)[row * (size_t)N + col] = f2bf(acc[mi][ni][i]);
        else       ((float*)Cv)[row * (size_t)N + col] = acc[mi][ni][i];
      }
}

// ---------------- RMSNorm + RoPE: qkv bf16 -> Q[h][t][d], K[h][t][d] (scale folded into Q) ----------------
__global__ __launch_bounds__(256) void k_rmsrope(const u16* __restrict__ qkv, const float* __restrict__ cosp,
                                                 const float* __restrict__ sinp, const float* __restrict__ qw,
                                                 const float* __restrict__ kw, u16* __restrict__ Qr,
                                                 u16* __restrict__ Kr){
  int t = blockIdx.x;
  int lane = threadIdx.x & 63, w = threadIdx.x >> 6;
  int hh = blockIdx.y * 4 + w;          // 0..39: 32 q heads + 8 k heads
  bool isq = hh < NQH;
  int hl = isq ? hh : hh - NQH;
  const u16* src = qkv + (size_t)t * QKVN + (isq ? hl * HD : NQH * HD + hl * HD);
  unsigned u = *(const unsigned*)(src + 2 * lane);       // d = 2*lane, 2*lane+1
  float x0 = bf2f((u16)(u & 0xffffu)), x1 = bf2f((u16)(u >> 16));
  float ss = x0 * x0 + x1 * x1;
#pragma unroll
  for (int m = 1; m < 64; m <<= 1) ss += __shfl_xor(ss, m);
  float rs = rsqrtf(ss * (1.f / HD) + 1e-6f);
  const float* wp = isq ? qw : kw;
  float w0 = wp[2 * lane], w1 = wp[2 * lane + 1];
  float xn0 = x0 * rs * w0, xn1 = x1 * rs * w1;
  float p0 = __shfl_xor(xn0, 32), p1 = __shfl_xor(xn1, 32);  // rotate-half partner
  int j0 = (2 * lane) & 63;
  float c0 = cosp[t * 64 + j0], c1 = cosp[t * 64 + j0 + 1];
  float s0 = sinp[t * 64 + j0], s1 = sinp[t * 64 + j0 + 1];
  float o0, o1;
  if (lane < 32){ o0 = xn0 * c0 - p0 * s0; o1 = xn1 * c1 - p1 * s1; }
  else          { o0 = xn0 * c0 + p0 * s0; o1 = xn1 * c1 + p1 * s1; }
  if (isq){ o0 *= 0.08838834764831845f; o1 *= 0.08838834764831845f; }  // D^-0.5
  u16* dst = isq ? (Qr + ((size_t)hl * SEQ + t) * HD) : (Kr + ((size_t)hl * SEQ + t) * HD);
  *(unsigned*)(dst + 2 * lane) = (unsigned)f2bf(o0) | ((unsigned)f2bf(o1) << 16);
}

// ---------------- V slice of qkv -> VT[h][d][t] bf16 ----------------
__global__ void k_vt(const u16* __restrict__ qkv, u16* __restrict__ VT){
  __shared__ u16 t[32][33];
  int t0 = blockIdx.x * 32, d0 = blockIdx.y * 32, hv = blockIdx.z;
  int tx = threadIdx.x, ty = threadIdx.y;
#pragma unroll
  for (int i = 0; i < 32; i += 8)
    t[ty + i][tx] = qkv[(size_t)(t0 + ty + i) * QKVN + (NQH + NKVH) * HD + hv * HD + d0 + tx];
  __syncthreads();
#pragma unroll
  for (int i = 0; i < 32; i += 8)
    VT[((size_t)hv * HD + d0 + ty + i) * SEQ + t0 + tx] = t[tx][ty + i];
}

// ---------------- causal GQA flash attention, KVBLK=128 counted-wait pipeline ----------------
// 512 blocks (8 waves): one 128-row q-tile per block, longest-first; kvg=bid&7.
// Per trip (128-wide KV tile): issue V(t) stage (single buf) + K(t+1) prefetch (dbuf)
// -> QK from Ksm[cur] -> softmax -> P -> vmcnt(4) [own V landed, K(t+1) still flying]
// -> raw s_barrier [all waves' V visible] -> PV -> vmcnt(0) [K(t+1), ~free: issued a
// full trip ago] -> raw s_barrier. No mid-loop hard drain; 2 barriers per 128 kv
// (was 4 + 2 implicit full drains). All waves active every trip (uniform barriers).
__global__ __launch_bounds__(512) void k_attn(const u16* __restrict__ Q, const u16* __restrict__ Kg,
                                              const u16* __restrict__ VTg, u16* __restrict__ AO){
  __shared__ __align__(16) u16 Ksm[2][128][128];  // 64 KB, granule-swizzled (key row&7)
  __shared__ __align__(16) u16 Vsm[128][128];     // 32 KB [d][kv], swizzled (key d&7)
  __shared__ __align__(16) u16 Psm[8][16][136];   // 34.8 KB per-wave P [q][kv]
  int tid = threadIdx.x, lane = tid & 63, wid = tid >> 6;
  int l16 = lane & 15, lhi = lane >> 4;
  int bid = blockIdx.x;
  int kvg = bid & 7, rr = bid >> 3;               // 64 blocks per kv-group
  int J = 15 - (rr >> 2);                         // longest-first
  int hq = kvg * 4 + (rr & 3);
  int qb = J * 128;
  const u16* Kh = Kg  + (size_t)kvg * SEQ * HD;
  const u16* Vh = VTg + (size_t)kvg * HD * SEQ;
  const u16* Qh = Q   + (size_t)hq * SEQ * HD;

  // Q fragments: wave owns rows qb + wid*16 .. +15
  bf16x8 qf[4];
#pragma unroll
  for (int ks = 0; ks < 4; ks++)
    qf[ks] = *(const bf16x8*)(Qh + (size_t)(qb + wid*16 + l16) * HD + ks*32 + lhi*8);

  const f32x4 vz = {0.f, 0.f, 0.f, 0.f};
  f32x4 o[8];
  float mrow[4], lrow[4];
#pragma unroll
  for (int n = 0; n < 8; n++) o[n] = vz;
#pragma unroll
  for (int i = 0; i < 4; i++){ mrow[i] = -1e30f; lrow[i] = 0.f; }

  // staging geometry: gload j covers 4 rows (256B each); lane -> rsub=lane>>4, granule=lane&15.
  // Source granule pre-swizzled with key (row&7) so linear LDS + swizzled read = identity.
  int rsub = lane >> 4, g = lane & 15;
  const u16 *Ks0, *Ks1, *Ks2, *Ks3, *Vs0, *Vs1, *Vs2, *Vs3;
  {
    int r0 = wid*16 + 0*4 + rsub, r1 = wid*16 + 1*4 + rsub;
    int r2 = wid*16 + 2*4 + rsub, r3 = wid*16 + 3*4 + rsub;
    Ks0 = Kh + (size_t)r0 * HD + ((g ^ (r0 & 7)) << 3);
    Ks1 = Kh + (size_t)r1 * HD + ((g ^ (r1 & 7)) << 3);
    Ks2 = Kh + (size_t)r2 * HD + ((g ^ (r2 & 7)) << 3);
    Ks3 = Kh + (size_t)r3 * HD + ((g ^ (r3 & 7)) << 3);
    Vs0 = Vh + (size_t)r0 * SEQ + ((g ^ (r0 & 7)) << 3);
    Vs1 = Vh + (size_t)r1 * SEQ + ((g ^ (r1 & 7)) << 3);
    Vs2 = Vh + (size_t)r2 * SEQ + ((g ^ (r2 & 7)) << 3);
    Vs3 = Vh + (size_t)r3 * SEQ + ((g ^ (r3 & 7)) << 3);
  }

  // prologue: stage K tile 0 -> Ksm[0]
  gload16(Ks0, &Ksm[0][wid*16 +  0][0]);
  gload16(Ks1, &Ksm[0][wid*16 +  4][0]);
  gload16(Ks2, &Ksm[0][wid*16 +  8][0]);
  gload16(Ks3, &Ksm[0][wid*16 + 12][0]);
  asm volatile("s_waitcnt vmcnt(0)" ::: "memory");
  __builtin_amdgcn_sched_barrier(0);
  __builtin_amdgcn_s_barrier();

  int ntr = J + 1;
  int wrow0 = qb + wid*16;
  for (int t = 0; t < ntr; t++){
    int cur = t & 1, nxt = cur ^ 1;
    int kt0 = t << 7;
    bool pf = (t + 1 < ntr);
    // V(t) stage FIRST (so vmcnt(4) retires it while K-prefetch stays in flight)
    gload16(Vs0 + kt0, &Vsm[wid*16 +  0][0]);
    gload16(Vs1 + kt0, &Vsm[wid*16 +  4][0]);
    gload16(Vs2 + kt0, &Vsm[wid*16 +  8][0]);
    gload16(Vs3 + kt0, &Vsm[wid*16 + 12][0]);
    if (pf){
      size_t ko = (size_t)(kt0 + 128) * HD;
      gload16(Ks0 + ko, &Ksm[nxt][wid*16 +  0][0]);
      gload16(Ks1 + ko, &Ksm[nxt][wid*16 +  4][0]);
      gload16(Ks2 + ko, &Ksm[nxt][wid*16 +  8][0]);
      gload16(Ks3 + ko, &Ksm[nxt][wid*16 + 12][0]);
    }
    // QK^T from Ksm[cur] (landed: drained before prev trip-end barrier)
    f32x4 s[8];
#pragma unroll
    for (int n = 0; n < 8; n++) s[n] = vz;
    const u16* kbase = &Ksm[cur][0][0];
    __builtin_amdgcn_s_setprio(1);
#pragma unroll
    for (int n = 0; n < 8; n++){
      int row = n*16 + l16, rxk = row & 7;
#pragma unroll
      for (int ks = 0; ks < 4; ks++){
        bf16x8 kf = *(const bf16x8*)(kbase + row*128 + (((ks*4 + lhi) ^ rxk) << 3));
        s[n] = mfma16(qf[ks], kf, s[n]);
      }
    }
    __builtin_amdgcn_s_setprio(0);
    // causal mask (only the diagonal trip has masked cols)
    if (kt0 + 127 > wrow0){
#pragma unroll
      for (int n = 0; n < 8; n++)
#pragma unroll
        for (int i = 0; i < 4; i++)
          if (kt0 + n*16 + l16 > wrow0 + lhi*4 + i) s[n][i] = -1e30f;
    }
    // online softmax (row q lives in 16 lanes sharing lhi*4+i)
#pragma unroll
    for (int i = 0; i < 4; i++){
      float tm = fmaxf(fmaxf(fmaxf(s[0][i], s[1][i]), fmaxf(s[2][i], s[3][i])),
                       fmaxf(fmaxf(s[4][i], s[5][i]), fmaxf(s[6][i], s[7][i])));
      tm = fmaxf(tm, __shfl_xor(tm, 1));
      tm = fmaxf(tm, __shfl_xor(tm, 2));
      tm = fmaxf(tm, __shfl_xor(tm, 4));
      tm = fmaxf(tm, __shfl_xor(tm, 8));
      float nm = fmaxf(mrow[i], tm);
      float sc = __expf(mrow[i] - nm);
      mrow[i] = nm;
      float rsum = 0.f;
#pragma unroll
      for (int n = 0; n < 8; n++){
        float p = __expf(s[n][i] - nm);
        s[n][i] = p;
        rsum += p;
      }
      rsum += __shfl_xor(rsum, 1);
      rsum += __shfl_xor(rsum, 2);
      rsum += __shfl_xor(rsum, 4);
      rsum += __shfl_xor(rsum, 8);
      lrow[i] = lrow[i] * sc + rsum;
#pragma unroll
      for (int n = 0; n < 8; n++) o[n][i] *= sc;
    }
    // P (D-layout) -> per-wave LDS (same-wave producer/consumer)
#pragma unroll
    for (int n = 0; n < 8; n++)
#pragma unroll
      for (int i = 0; i < 4; i++)
        Psm[wid][lhi*4 + i][n*16 + l16] = f2bf(s[n][i]);
    // V visibility: each wave drains OWN V (K-prefetch stays in flight), then barrier
    if (pf) asm volatile("s_waitcnt vmcnt(4)" ::: "memory");
    else    asm volatile("s_waitcnt vmcnt(0)" ::: "memory");
    __builtin_amdgcn_sched_barrier(0);
    __builtin_amdgcn_s_barrier();
    __builtin_amdgcn_sched_barrier(0);
    // PV from Vsm (swizzled) and Psm
    __builtin_amdgcn_s_setprio(1);
#pragma unroll
    for (int ksv = 0; ksv < 4; ksv++){
      bf16x8 pa = *(const bf16x8*)&Psm[wid][l16][ksv*32 + lhi*8];
#pragma unroll
      for (int n = 0; n < 8; n++){
        int row = n*16 + l16;
        bf16x8 vb = *(const bf16x8*)(&Vsm[0][0] + row*128 + (((ksv*4 + lhi) ^ (row & 7)) << 3));
        o[n] = mfma16(pa, vb, o[n]);
      }
    }
    __builtin_amdgcn_s_setprio(0);
    // trip end: drain own K(t+1) (issued a full trip ago, ~free) + barrier
    asm volatile("s_waitcnt vmcnt(0)" ::: "memory");
    __builtin_amdgcn_sched_barrier(0);
    __builtin_amdgcn_s_barrier();
  }
  // epilogue: O /= l, write bf16 to AO[t][hq*128 + d]
  float inv[4];
#pragma unroll
  for (int i = 0; i < 4; i++) inv[i] = 1.f / lrow[i];
#pragma unroll
  for (int n = 0; n < 8; n++)
#pragma unroll
    for (int i = 0; i < 4; i++){
      int trow = wrow0 + lhi*4 + i;
      AO[(size_t)trow * HID + hq * HD + n*16 + l16] = f2bf(o[n][i] * inv[i]);
    }
}

// ---------------- launch ----------------
extern "C" void kernel_launch(void* const* d_in, const int* in_sizes, int n_in,
                              void* d_out, int out_size, void* d_ws, size_t ws_size,
                              hipStream_t stream){
  const float* hs   = (const float*)d_in[0];
  const float* cosp = (const float*)d_in[1];
  const float* sinp = (const float*)d_in[2];
  const float* wqkv = (const float*)d_in[3];
  const float* wo   = (const float*)d_in[4];
  const float* qw   = (const float*)d_in[5];
  const float* kw   = (const float*)d_in[6];
  float* out = (float*)d_out;
  char* ws = (char*)d_ws;
  // workspace layout (128 MB total); WOT reuses XB region after GEMM1; SCR (split-K
  // fp32 partial, 33.55 MB) reuses [33.5M, 67.1M) = rest of WQKVT region, dead after GEMM1.
  u16* XB    = (u16*)(ws + 0);            // 16.8 MB  X bf16 [2048][4096]
  u16* WQKVT = (u16*)(ws + 16777216);     // 50.3 MB  WqkvT bf16 [6144][4096]
  u16* WOT   = (u16*)(ws + 0);            // 33.6 MB  WoT bf16 [4096][4096] (after GEMM1)
  float* SCR = (float*)(ws + 33554432);   // 33.6 MB  fp32 partial [2048][4096]
  u16* QKV   = (u16*)(ws + 67108864);     // 25.2 MB  qkv bf16 [2048][6144]
  u16* QR    = (u16*)(ws + 92274688);     // 16.8 MB  Q bf16 [32][2048][128]
  u16* KR    = (u16*)(ws + 109051904);    //  4.2 MB  K bf16 [8][2048][128]
  u16* VTB   = (u16*)(ws + 113246208);    //  4.2 MB  VT bf16 [8][128][2048]
  u16* AOB   = (u16*)(ws + 117440512);    // 16.8 MB  attn out bf16 [2048][4096]

  k_cvt<<<(SEQ * HID / 4 + 255) / 256, 256, 0, stream>>>(hs, XB, SEQ * HID / 4);
  k_transpose_cvt<<<dim3(QKVN / 32, HID / 32), dim3(32, 8), 0, stream>>>(wqkv, WQKVT, HID, QKVN);
  // GEMM1: 192 blocks = 8 XCD x (3 bcol x 8 brow)
  k_gemm<1, 1, 3, 8><<<192, 512, 0, stream>>>(XB, WQKVT, QKV, nullptr, SEQ, QKVN, HID);
  k_transpose_cvt<<<dim3(HID / 32, HID / 32), dim3(32, 8), 0, stream>>>(wo, WOT, HID, HID);
  k_rmsrope<<<dim3(SEQ, 10), 256, 0, stream>>>(QKV, cosp, sinp, qw, kw, QR, KR);
  k_vt<<<dim3(SEQ / 32, HD / 32, NKVH), dim3(32, 8), 0, stream>>>(QKV, VTB);
  k_attn<<<512, 512, 0, stream>>>(QR, KR, VTB, AOB);
  // GEMM2: 256 blocks = 8 XCD x (2 bcol x 8 brow x 2 kz), split-K=2
  k_gemm<0, 2, 2, 8><<<256, 512, 0, stream>>>(AOB, WOT, out, SCR, SEQ, HID, HID);
  k_addf<<<SEQ * HID / 4 / 256, 256, 0, stream>>>(SCR, out, SEQ * HID / 4);
}

// Round 12
// 344.918 us; speedup vs baseline: 1.0954x; 1.0388x over previous
//
#include <hip/hip_runtime.h>
#include <stdint.h>

#define SEQ   2048
#define HID   4096
#define NQH   32
#define NKVH  8
#define HD    128
#define QKVN  6144   // (32 + 2*8) * 128

typedef uint16_t u16;
typedef __attribute__((ext_vector_type(8))) short bf16x8;
typedef __attribute__((ext_vector_type(4))) float f32x4;
typedef __attribute__((ext_vector_type(4))) unsigned int u32x4;

static __device__ __forceinline__ float bf2f(u16 h){
  union { float f; unsigned int u; } v; v.u = ((unsigned int)h) << 16; return v.f;
}
static __device__ __forceinline__ u16 f2bf(float f){
  unsigned int u = __float_as_uint(f);
  return (u16)((u + 0x7fffu + ((u >> 16) & 1u)) >> 16);  // RNE, finite inputs only
}
static __device__ __forceinline__ f32x4 mfma16(bf16x8 a, bf16x8 b, f32x4 c){
  return __builtin_amdgcn_mfma_f32_16x16x32_bf16(a, b, c, 0, 0, 0);
}
static __device__ __forceinline__ void gload16(const void* g, void* l){
  __builtin_amdgcn_global_load_lds((const __attribute__((address_space(1))) void*)g,
                                   (__attribute__((address_space(3))) void*)l, 16, 0, 0);
}

// ---------------- fp32 -> bf16 elementwise (n4 = n/4) ----------------
__global__ void k_cvt(const float* __restrict__ src, u16* __restrict__ dst, int n4){
  int i = blockIdx.x * blockDim.x + threadIdx.x;
  if (i >= n4) return;
  float4 v = ((const float4*)src)[i];
  uint2 o;
  o.x = (unsigned)f2bf(v.x) | ((unsigned)f2bf(v.y) << 16);
  o.y = (unsigned)f2bf(v.z) | ((unsigned)f2bf(v.w) << 16);
  ((uint2*)dst)[i] = o;
}

// ---------------- o += a (fp32, n4 = n/4) ----------------
__global__ void k_addf(const float* __restrict__ a, float* __restrict__ o, int n4){
  int i = blockIdx.x * blockDim.x + threadIdx.x;
  if (i >= n4) return;
  float4 x = ((const float4*)o)[i];
  float4 y = ((const float4*)a)[i];
  x.x += y.x; x.y += y.y; x.z += y.z; x.w += y.w;
  ((float4*)o)[i] = x;
}

// ---------------- src[K][N] fp32 -> dst[N][K] bf16 (transpose-convert) ----------------
__global__ void k_transpose_cvt(const float* __restrict__ src, u16* __restrict__ dst, int K, int N){
  __shared__ float t[32][33];
  int n0 = blockIdx.x * 32, k0 = blockIdx.y * 32;
  int tx = threadIdx.x, ty = threadIdx.y;
#pragma unroll
  for (int i = 0; i < 32; i += 8)
    t[ty + i][tx] = src[(size_t)(k0 + ty + i) * N + n0 + tx];
  __syncthreads();
#pragma unroll
  for (int i = 0; i < 32; i += 8)
    dst[(size_t)(n0 + ty + i) * K + k0 + tx] = f2bf(t[tx][ty + i]);
}

// ---------------- C[M][N] = A[M][K] @ Bt[N][K]^T, bf16 in, OUTBF? bf16 : fp32 out ----------------
// m201-faithful 8-phase schedule: BM=BN=256, BK=64, 512 thr / 8 waves (2M x 4N),
// wave tile 128x64, TWO K-tiles per iteration, 8 phases of 16-MFMA quadrant clusters.
// LDS = 2 tile-bufs x 2 halves x 128x64 per matrix (128 KB). Staging = 1 half-tile
// (2 gloads/thread) per phase, slots: P0:(t+1)A0 P1:(t+1)A1 P2:(t+2)B0 P3:(t+2)B1
// P4:(t+2)A0 P5:(t+2)A1 P6:(t+3)B0 P7:(t+3)B1 -- every write >=1 barrier-pair after
// that region's last ds_read. COUNTED vmcnt(4) twice per iter (pre-P0 / pre-P4, FIFO:
// allow the 2 newest half-tiles); vmcnt(0) only at cold prologue + final pre-P4.
// Granule XOR swizzle g^=(row&7) both sides (measured: 0 bank conflicts).
template<int OUTBF, int SPLITK, int XBC, int NBY>
__global__ __launch_bounds__(512) void k_gemm(const u16* __restrict__ A, const u16* __restrict__ Bt,
                                              void* __restrict__ Cv0, void* __restrict__ Cv1,
                                              int M, int N, int K){
  __shared__ __align__(16) u16 Asm[2][2][128][64];   // [tilebuf][half][row][k] 64 KB
  __shared__ __align__(16) u16 Bsm[2][2][128][64];   // 64 KB
  const int tid = threadIdx.x, lane = tid & 63, wid = tid >> 6;
  const int wm = wid >> 2, wn = wid & 3;             // 2 x 4 wave grid
  const int l16 = lane & 15, lhi = lane >> 4;
  const int rx = l16 & 7;                             // read-side swizzle key (= row&7)
  // XCD-locality block mapping (bijective): bid -> (bcol, brow, kz)
  const int bid = blockIdx.x;
  const int xcd = bid & 7, jj = bid >> 3;
  const int bcol_i = xcd * XBC + jj % XBC;
  const int rest = jj / XBC;
  const int brow_i = rest % NBY;
  const int kz = (SPLITK > 1) ? (rest / NBY) : 0;
  const size_t brow = (size_t)brow_i * 256, bcol = (size_t)bcol_i * 256;
  const int kbeg = kz * (K / SPLITK);
  void* Cv = (kz == 0) ? Cv0 : Cv1;

  const f32x4 vz = {0.f, 0.f, 0.f, 0.f};
  f32x4 acc[8][4];
#pragma unroll
  for (int m = 0; m < 8; m++)
#pragma unroll
    for (int n = 0; n < 4; n++) acc[m][n] = vz;

  // staging geometry: one gload round = 64 rows (8 rows/wave); granule = lane&7,
  // source pre-swizzled with key (row&7)=srow.
  const int srow = lane >> 3;
  const int sg   = (lane & 7) ^ srow;
  const u16* Ags = A  + (brow + wid*8 + srow) * (size_t)K + sg*8 + kbeg;
  const u16* Bgs = Bt + (bcol + wid*8 + srow) * (size_t)K + sg*8 + kbeg;
  const int NT = (K / SPLITK) >> 6;   // K-tiles (even)
  const int NU = NT >> 1;             // iterations (2 tiles each)

  // fragment-read macros (buf = tile&1)
#define FRA(buf, mi, kh) (*(const bf16x8*)&Asm[buf][wm][(mi)*16 + l16][(((kh)*4 + lhi) ^ rx) << 3])
#define FRB(buf, ni, kh) (*(const bf16x8*)&Bsm[buf][wn >> 1][(wn & 1)*64 + (ni)*16 + l16][(((kh)*4 + lhi) ^ rx) << 3])
  // stage one half-tile (2 gloads/thread), guarded
#define STG_A(tile, half) do{ if ((tile) < NT){                                  \
    const size_t ko_ = (size_t)((half)*128) * K + (size_t)(tile) * 64;           \
    gload16(Ags + ko_,                &Asm[(tile)&1][half][wid*8][0]);           \
    gload16(Ags + ko_ + (size_t)64*K, &Asm[(tile)&1][half][64 + wid*8][0]); } }while(0)
#define STG_B(tile, half) do{ if ((tile) < NT){                                  \
    const size_t ko_ = (size_t)((half)*128) * K + (size_t)(tile) * 64;           \
    gload16(Bgs + ko_,                &Bsm[(tile)&1][half][wid*8][0]);           \
    gload16(Bgs + ko_ + (size_t)64*K, &Bsm[(tile)&1][half][64 + wid*8][0]); } }while(0)

  // prologue: t0{B0,B1,A0,A1}, t1{B0,B1}; confirm t0 (allow t1's 2 halves = 4 gloads)
  STG_B(0, 0); STG_B(0, 1); STG_A(0, 0); STG_A(0, 1); STG_B(1, 0); STG_B(1, 1);
  asm volatile("s_waitcnt vmcnt(4)" ::: "memory");
  __builtin_amdgcn_sched_barrier(0);
  __builtin_amdgcn_s_barrier();

  bf16x8 fA[4][2], fB01[2][2], fB23[2][2];
  for (int u = 0; u < NU; ++u){
    const int t = 2 * u;
    // ========== P0: Q0(t) = mi0-3 x ni0-1 ==========
#pragma unroll
    for (int mi = 0; mi < 4; ++mi){ fA[mi][0] = FRA(0, mi, 0); fA[mi][1] = FRA(0, mi, 1); }
#pragma unroll
    for (int ni = 0; ni < 2; ++ni){ fB01[ni][0] = FRB(0, ni, 0); fB01[ni][1] = FRB(0, ni, 1); }
    STG_A(t + 1, 0);
    asm volatile("s_waitcnt lgkmcnt(8)" ::: "memory");
    __builtin_amdgcn_s_barrier();
    asm volatile("s_waitcnt lgkmcnt(0)" ::: "memory");
    __builtin_amdgcn_sched_barrier(0);
    __builtin_amdgcn_s_setprio(1);
#pragma unroll
    for (int kh = 0; kh < 2; ++kh)
#pragma unroll
      for (int mi = 0; mi < 4; ++mi)
#pragma unroll
        for (int ni = 0; ni < 2; ++ni)
          acc[mi][ni] = mfma16(fA[mi][kh], fB01[ni][kh], acc[mi][ni]);
    __builtin_amdgcn_s_setprio(0);
    __builtin_amdgcn_s_barrier();
    // ========== P1: Q1(t) = mi0-3 x ni2-3 ==========
#pragma unroll
    for (int ni = 0; ni < 2; ++ni){ fB23[ni][0] = FRB(0, 2 + ni, 0); fB23[ni][1] = FRB(0, 2 + ni, 1); }
    STG_A(t + 1, 1);
    __builtin_amdgcn_s_barrier();
    asm volatile("s_waitcnt lgkmcnt(0)" ::: "memory");
    __builtin_amdgcn_sched_barrier(0);
    __builtin_amdgcn_s_setprio(1);
#pragma unroll
    for (int kh = 0; kh < 2; ++kh)
#pragma unroll
      for (int mi = 0; mi < 4; ++mi)
#pragma unroll
        for (int ni = 0; ni < 2; ++ni)
          acc[mi][2 + ni] = mfma16(fA[mi][kh], fB23[ni][kh], acc[mi][2 + ni]);
    __builtin_amdgcn_s_setprio(0);
    __builtin_amdgcn_s_barrier();
    // ========== P2: Q2(t) = mi4-7 x ni0-1 ==========
#pragma unroll
    for (int mi = 0; mi < 4; ++mi){ fA[mi][0] = FRA(0, 4 + mi, 0); fA[mi][1] = FRA(0, 4 + mi, 1); }
    STG_B(t + 2, 0);
    __builtin_amdgcn_s_barrier();
    asm volatile("s_waitcnt lgkmcnt(0)" ::: "memory");
    __builtin_amdgcn_sched_barrier(0);
    __builtin_amdgcn_s_setprio(1);
#pragma unroll
    for (int kh = 0; kh < 2; ++kh)
#pragma unroll
      for (int mi = 0; mi < 4; ++mi)
#pragma unroll
        for (int ni = 0; ni < 2; ++ni)
          acc[4 + mi][ni] = mfma16(fA[mi][kh], fB01[ni][kh], acc[4 + mi][ni]);
    __builtin_amdgcn_s_setprio(0);
    __builtin_amdgcn_s_barrier();
    // ========== P3: Q3(t) = mi4-7 x ni2-3; pre-P4 counted wait ==========
    STG_B(t + 2, 1);
    __builtin_amdgcn_s_barrier();
    asm volatile("s_waitcnt lgkmcnt(0)" ::: "memory");
    __builtin_amdgcn_sched_barrier(0);
    __builtin_amdgcn_s_setprio(1);
#pragma unroll
    for (int kh = 0; kh < 2; ++kh)
#pragma unroll
      for (int mi = 0; mi < 4; ++mi)
#pragma unroll
        for (int ni = 0; ni < 2; ++ni)
          acc[4 + mi][2 + ni] = mfma16(fA[mi][kh], fB23[ni][kh], acc[4 + mi][2 + ni]);
    __builtin_amdgcn_s_setprio(0);
    if (u == NU - 1) asm volatile("s_waitcnt vmcnt(0)" ::: "memory");  // tail: t+1 fully landed
    else             asm volatile("s_waitcnt vmcnt(4)" ::: "memory");  // allow (t+2)B0,B1
    __builtin_amdgcn_sched_barrier(0);
    __builtin_amdgcn_s_barrier();
    // ========== P4: Q0(t+1) ==========
#pragma unroll
    for (int mi = 0; mi < 4; ++mi){ fA[mi][0] = FRA(1, mi, 0); fA[mi][1] = FRA(1, mi, 1); }
#pragma unroll
    for (int ni = 0; ni < 2; ++ni){ fB01[ni][0] = FRB(1, ni, 0); fB01[ni][1] = FRB(1, ni, 1); }
    STG_A(t + 2, 0);
    asm volatile("s_waitcnt lgkmcnt(8)" ::: "memory");
    __builtin_amdgcn_s_barrier();
    asm volatile("s_waitcnt lgkmcnt(0)" ::: "memory");
    __builtin_amdgcn_sched_barrier(0);
    __builtin_amdgcn_s_setprio(1);
#pragma unroll
    for (int kh = 0; kh < 2; ++kh)
#pragma unroll
      for (int mi = 0; mi < 4; ++mi)
#pragma unroll
        for (int ni = 0; ni < 2; ++ni)
          acc[mi][ni] = mfma16(fA[mi][kh], fB01[ni][kh], acc[mi][ni]);
    __builtin_amdgcn_s_setprio(0);
    __builtin_amdgcn_s_barrier();
    // ========== P5: Q1(t+1) ==========
#pragma unroll
    for (int ni = 0; ni < 2; ++ni){ fB23[ni][0] = FRB(1, 2 + ni, 0); fB23[ni][1] = FRB(1, 2 + ni, 1); }
    STG_A(t + 2, 1);
    __builtin_amdgcn_s_barrier();
    asm volatile("s_waitcnt lgkmcnt(0)" ::: "memory");
    __builtin_amdgcn_sched_barrier(0);
    __builtin_amdgcn_s_setprio(1);
#pragma unroll
    for (int kh = 0; kh < 2; ++kh)
#pragma unroll
      for (int mi = 0; mi < 4; ++mi)
#pragma unroll
        for (int ni = 0; ni < 2; ++ni)
          acc[mi][2 + ni] = mfma16(fA[mi][kh], fB23[ni][kh], acc[mi][2 + ni]);
    __builtin_amdgcn_s_setprio(0);
    __builtin_amdgcn_s_barrier();
    // ========== P6: Q2(t+1) ==========
#pragma unroll
    for (int mi = 0; mi < 4; ++mi){ fA[mi][0] = FRA(1, 4 + mi, 0); fA[mi][1] = FRA(1, 4 + mi, 1); }
    STG_B(t + 3, 0);
    __builtin_amdgcn_s_barrier();
    asm volatile("s_waitcnt lgkmcnt(0)" ::: "memory");
    __builtin_amdgcn_sched_barrier(0);
    __builtin_amdgcn_s_setprio(1);
#pragma unroll
    for (int kh = 0; kh < 2; ++kh)
#pragma unroll
      for (int mi = 0; mi < 4; ++mi)
#pragma unroll
        for (int ni = 0; ni < 2; ++ni)
          acc[4 + mi][ni] = mfma16(fA[mi][kh], fB01[ni][kh], acc[4 + mi][ni]);
    __builtin_amdgcn_s_setprio(0);
    __builtin_amdgcn_s_barrier();
    // ========== P7: Q3(t+1); pre-P0 counted wait ==========
    STG_B(t + 3, 1);
    __builtin_amdgcn_s_barrier();
    asm volatile("s_waitcnt lgkmcnt(0)" ::: "memory");
    __builtin_amdgcn_sched_barrier(0);
    __builtin_amdgcn_s_setprio(1);
#pragma unroll
    for (int kh = 0; kh < 2; ++kh)
#pragma unroll
      for (int mi = 0; mi < 4; ++mi)
#pragma unroll
        for (int ni = 0; ni < 2; ++ni)
          acc[4 + mi][2 + ni] = mfma16(fA[mi][kh], fB23[ni][kh], acc[4 + mi][2 + ni]);
    __builtin_amdgcn_s_setprio(0);
    asm volatile("s_waitcnt vmcnt(4)" ::: "memory");   // confirm t+2; allow (t+3)B0,B1
    __builtin_amdgcn_sched_barrier(0);
    __builtin_amdgcn_s_barrier();
  }
#undef FRA
#undef FRB
#undef STG_A
#undef STG_B

  // epilogue: C/D layout col=l16, row=lhi*4+i
#pragma unroll
  for (int mi = 0; mi < 8; mi++)
#pragma unroll
    for (int ni = 0; ni < 4; ni++)
#pragma unroll
      for (int i = 0; i < 4; i++){
        size_t row = brow + wm*128 + mi*16 + lhi*4 + i;
        size_t col = bcol + wn*64 + ni*16 + l16;
        if (OUTBF) ((u16*)Cv)[row * (size_t)N + col] = f2bf(acc[mi][ni][i]);
        else       ((float*)Cv)[row * (size_t)N + col] = acc[mi][ni][i];
      }
}

// ---------------- RMSNorm + RoPE: qkv bf16 -> Q[h][t][d], K[h][t][d] (scale folded into Q) ----------------
__global__ __launch_bounds__(256) void k_rmsrope(const u16* __restrict__ qkv, const float* __restrict__ cosp,
                                                 const float* __restrict__ sinp, const float* __restrict__ qw,
                                                 const float* __restrict__ kw, u16* __restrict__ Qr,
                                                 u16* __restrict__ Kr){
  int t = blockIdx.x;
  int lane = threadIdx.x & 63, w = threadIdx.x >> 6;
  int hh = blockIdx.y * 4 + w;          // 0..39: 32 q heads + 8 k heads
  bool isq = hh < NQH;
  int hl = isq ? hh : hh - NQH;
  const u16* src = qkv + (size_t)t * QKVN + (isq ? hl * HD : NQH * HD + hl * HD);
  unsigned u = *(const unsigned*)(src + 2 * lane);       // d = 2*lane, 2*lane+1
  float x0 = bf2f((u16)(u & 0xffffu)), x1 = bf2f((u16)(u >> 16));
  float ss = x0 * x0 + x1 * x1;
#pragma unroll
  for (int m = 1; m < 64; m <<= 1) ss += __shfl_xor(ss, m);
  float rs = rsqrtf(ss * (1.f / HD) + 1e-6f);
  const float* wp = isq ? qw : kw;
  float w0 = wp[2 * lane], w1 = wp[2 * lane + 1];
  float xn0 = x0 * rs * w0, xn1 = x1 * rs * w1;
  float p0 = __shfl_xor(xn0, 32), p1 = __shfl_xor(xn1, 32);  // rotate-half partner
  int j0 = (2 * lane) & 63;
  float c0 = cosp[t * 64 + j0], c1 = cosp[t * 64 + j0 + 1];
  float s0 = sinp[t * 64 + j0], s1 = sinp[t * 64 + j0 + 1];
  float o0, o1;
  if (lane < 32){ o0 = xn0 * c0 - p0 * s0; o1 = xn1 * c1 - p1 * s1; }
  else          { o0 = xn0 * c0 + p0 * s0; o1 = xn1 * c1 + p1 * s1; }
  if (isq){ o0 *= 0.08838834764831845f; o1 *= 0.08838834764831845f; }  // D^-0.5
  u16* dst = isq ? (Qr + ((size_t)hl * SEQ + t) * HD) : (Kr + ((size_t)hl * SEQ + t) * HD);
  *(unsigned*)(dst + 2 * lane) = (unsigned)f2bf(o0) | ((unsigned)f2bf(o1) << 16);
}

// ---------------- V slice of qkv -> VT[h][d][t] bf16 ----------------
__global__ void k_vt(const u16* __restrict__ qkv, u16* __restrict__ VT){
  __shared__ u16 t[32][33];
  int t0 = blockIdx.x * 32, d0 = blockIdx.y * 32, hv = blockIdx.z;
  int tx = threadIdx.x, ty = threadIdx.y;
#pragma unroll
  for (int i = 0; i < 32; i += 8)
    t[ty + i][tx] = qkv[(size_t)(t0 + ty + i) * QKVN + (NQH + NKVH) * HD + hv * HD + d0 + tx];
  __syncthreads();
#pragma unroll
  for (int i = 0; i < 32; i += 8)
    VT[((size_t)hv * HD + d0 + ty + i) * SEQ + t0 + tx] = t[tx][ty + i];
}

// ---------------- causal GQA flash attention, KVBLK=128 counted-wait pipeline ----------------
// (r11 structure, unchanged: best measured)
__global__ __launch_bounds__(512) void k_attn(const u16* __restrict__ Q, const u16* __restrict__ Kg,
                                              const u16* __restrict__ VTg, u16* __restrict__ AO){
  __shared__ __align__(16) u16 Ksm[2][128][128];  // 64 KB, granule-swizzled (key row&7)
  __shared__ __align__(16) u16 Vsm[128][128];     // 32 KB [d][kv], swizzled (key d&7)
  __shared__ __align__(16) u16 Psm[8][16][136];   // 34.8 KB per-wave P [q][kv]
  int tid = threadIdx.x, lane = tid & 63, wid = tid >> 6;
  int l16 = lane & 15, lhi = lane >> 4;
  int bid = blockIdx.x;
  int kvg = bid & 7, rr = bid >> 3;               // 64 blocks per kv-group
  int J = 15 - (rr >> 2);                         // longest-first
  int hq = kvg * 4 + (rr & 3);
  int qb = J * 128;
  const u16* Kh = Kg  + (size_t)kvg * SEQ * HD;
  const u16* Vh = VTg + (size_t)kvg * HD * SEQ;
  const u16* Qh = Q   + (size_t)hq * SEQ * HD;

  bf16x8 qf[4];
#pragma unroll
  for (int ks = 0; ks < 4; ks++)
    qf[ks] = *(const bf16x8*)(Qh + (size_t)(qb + wid*16 + l16) * HD + ks*32 + lhi*8);

  const f32x4 vz = {0.f, 0.f, 0.f, 0.f};
  f32x4 o[8];
  float mrow[4], lrow[4];
#pragma unroll
  for (int n = 0; n < 8; n++) o[n] = vz;
#pragma unroll
  for (int i = 0; i < 4; i++){ mrow[i] = -1e30f; lrow[i] = 0.f; }

  int rsub = lane >> 4, g = lane & 15;
  const u16 *Ks0, *Ks1, *Ks2, *Ks3, *Vs0, *Vs1, *Vs2, *Vs3;
  {
    int r0 = wid*16 + 0*4 + rsub, r1 = wid*16 + 1*4 + rsub;
    int r2 = wid*16 + 2*4 + rsub, r3 = wid*16 + 3*4 + rsub;
    Ks0 = Kh + (size_t)r0 * HD + ((g ^ (r0 & 7)) << 3);
    Ks1 = Kh + (size_t)r1 * HD + ((g ^ (r1 & 7)) << 3);
    Ks2 = Kh + (size_t)r2 * HD + ((g ^ (r2 & 7)) << 3);
    Ks3 = Kh + (size_t)r3 * HD + ((g ^ (r3 & 7)) << 3);
    Vs0 = Vh + (size_t)r0 * SEQ + ((g ^ (r0 & 7)) << 3);
    Vs1 = Vh + (size_t)r1 * SEQ + ((g ^ (r1 & 7)) << 3);
    Vs2 = Vh + (size_t)r2 * SEQ + ((g ^ (r2 & 7)) << 3);
    Vs3 = Vh + (size_t)r3 * SEQ + ((g ^ (r3 & 7)) << 3);
  }

  gload16(Ks0, &Ksm[0][wid*16 +  0][0]);
  gload16(Ks1, &Ksm[0][wid*16 +  4][0]);
  gload16(Ks2, &Ksm[0][wid*16 +  8][0]);
  gload16(Ks3, &Ksm[0][wid*16 + 12][0]);
  asm volatile("s_waitcnt vmcnt(0)" ::: "memory");
  __builtin_amdgcn_sched_barrier(0);
  __builtin_amdgcn_s_barrier();

  int ntr = J + 1;
  int wrow0 = qb + wid*16;
  for (int t = 0; t < ntr; t++){
    int cur = t & 1, nxt = cur ^ 1;
    int kt0 = t << 7;
    bool pf = (t + 1 < ntr);
    gload16(Vs0 + kt0, &Vsm[wid*16 +  0][0]);
    gload16(Vs1 + kt0, &Vsm[wid*16 +  4][0]);
    gload16(Vs2 + kt0, &Vsm[wid*16 +  8][0]);
    gload16(Vs3 + kt0, &Vsm[wid*16 + 12][0]);
    if (pf){
      size_t ko = (size_t)(kt0 + 128) * HD;
      gload16(Ks0 + ko, &Ksm[nxt][wid*16 +  0][0]);
      gload16(Ks1 + ko, &Ksm[nxt][wid*16 +  4][0]);
      gload16(Ks2 + ko, &Ksm[nxt][wid*16 +  8][0]);
      gload16(Ks3 + ko, &Ksm[nxt][wid*16 + 12][0]);
    }
    f32x4 s[8];
#pragma unroll
    for (int n = 0; n < 8; n++) s[n] = vz;
    const u16* kbase = &Ksm[cur][0][0];
    __builtin_amdgcn_s_setprio(1);
#pragma unroll
    for (int n = 0; n < 8; n++){
      int row = n*16 + l16, rxk = row & 7;
#pragma unroll
      for (int ks = 0; ks < 4; ks++){
        bf16x8 kf = *(const bf16x8*)(kbase + row*128 + (((ks*4 + lhi) ^ rxk) << 3));
        s[n] = mfma16(qf[ks], kf, s[n]);
      }
    }
    __builtin_amdgcn_s_setprio(0);
    if (kt0 + 127 > wrow0){
#pragma unroll
      for (int n = 0; n < 8; n++)
#pragma unroll
        for (int i = 0; i < 4; i++)
          if (kt0 + n*16 + l16 > wrow0 + lhi*4 + i) s[n][i] = -1e30f;
    }
#pragma unroll
    for (int i = 0; i < 4; i++){
      float tm = fmaxf(fmaxf(fmaxf(s[0][i], s[1][i]), fmaxf(s[2][i], s[3][i])),
                       fmaxf(fmaxf(s[4][i], s[5][i]), fmaxf(s[6][i], s[7][i])));
      tm = fmaxf(tm, __shfl_xor(tm, 1));
      tm = fmaxf(tm, __shfl_xor(tm, 2));
      tm = fmaxf(tm, __shfl_xor(tm, 4));
      tm = fmaxf(tm, __shfl_xor(tm, 8));
      float nm = fmaxf(mrow[i], tm);
      float sc = __expf(mrow[i] - nm);
      mrow[i] = nm;
      float rsum = 0.f;
#pragma unroll
      for (int n = 0; n < 8; n++){
        float p = __expf(s[n][i] - nm);
        s[n][i] = p;
        rsum += p;
      }
      rsum += __shfl_xor(rsum, 1);
      rsum += __shfl_xor(rsum, 2);
      rsum += __shfl_xor(rsum, 4);
      rsum += __shfl_xor(rsum, 8);
      lrow[i] = lrow[i] * sc + rsum;
#pragma unroll
      for (int n = 0; n < 8; n++) o[n][i] *= sc;
    }
#pragma unroll
    for (int n = 0; n < 8; n++)
#pragma unroll
      for (int i = 0; i < 4; i++)
        Psm[wid][lhi*4 + i][n*16 + l16] = f2bf(s[n][i]);
    if (pf) asm volatile("s_waitcnt vmcnt(4)" ::: "memory");
    else    asm volatile("s_waitcnt vmcnt(0)" ::: "memory");
    __builtin_amdgcn_sched_barrier(0);
    __builtin_amdgcn_s_barrier();
    __builtin_amdgcn_sched_barrier(0);
    __builtin_amdgcn_s_setprio(1);
#pragma unroll
    for (int ksv = 0; ksv < 4; ksv++){
      bf16x8 pa = *(const bf16x8*)&Psm[wid][l16][ksv*32 + lhi*8];
#pragma unroll
      for (int n = 0; n < 8; n++){
        int row = n*16 + l16;
        bf16x8 vb = *(const bf16x8*)(&Vsm[0][0] + row*128 + (((ksv*4 + lhi) ^ (row & 7)) << 3));
        o[n] = mfma16(pa, vb, o[n]);
      }
    }
    __builtin_amdgcn_s_setprio(0);
    asm volatile("s_waitcnt vmcnt(0)" ::: "memory");
    __builtin_amdgcn_sched_barrier(0);
    __builtin_amdgcn_s_barrier();
  }
  float inv[4];
#pragma unroll
  for (int i = 0; i < 4; i++) inv[i] = 1.f / lrow[i];
#pragma unroll
  for (int n = 0; n < 8; n++)
#pragma unroll
    for (int i = 0; i < 4; i++){
      int trow = wrow0 + lhi*4 + i;
      AO[(size_t)trow * HID + hq * HD + n*16 + l16] = f2bf(o[n][i] * inv[i]);
    }
}

// ---------------- launch ----------------
extern "C" void kernel_launch(void* const* d_in, const int* in_sizes, int n_in,
                              void* d_out, int out_size, void* d_ws, size_t ws_size,
                              hipStream_t stream){
  const float* hs   = (const float*)d_in[0];
  const float* cosp = (const float*)d_in[1];
  const float* sinp = (const float*)d_in[2];
  const float* wqkv = (const float*)d_in[3];
  const float* wo   = (const float*)d_in[4];
  const float* qw   = (const float*)d_in[5];
  const float* kw   = (const float*)d_in[6];
  float* out = (float*)d_out;
  char* ws = (char*)d_ws;
  // workspace layout (128 MB total); WOT reuses XB region after GEMM1; SCR (split-K
  // fp32 partial, 33.55 MB) reuses [33.5M, 67.1M) = rest of WQKVT region, dead after GEMM1.
  u16* XB    = (u16*)(ws + 0);            // 16.8 MB  X bf16 [2048][4096]
  u16* WQKVT = (u16*)(ws + 16777216);     // 50.3 MB  WqkvT bf16 [6144][4096]
  u16* WOT   = (u16*)(ws + 0);            // 33.6 MB  WoT bf16 [4096][4096] (after GEMM1)
  float* SCR = (float*)(ws + 33554432);   // 33.6 MB  fp32 partial [2048][4096]
  u16* QKV   = (u16*)(ws + 67108864);     // 25.2 MB  qkv bf16 [2048][6144]
  u16* QR    = (u16*)(ws + 92274688);     // 16.8 MB  Q bf16 [32][2048][128]
  u16* KR    = (u16*)(ws + 109051904);    //  4.2 MB  K bf16 [8][2048][128]
  u16* VTB   = (u16*)(ws + 113246208);    //  4.2 MB  VT bf16 [8][128][2048]
  u16* AOB   = (u16*)(ws + 117440512);    // 16.8 MB  attn out bf16 [2048][4096]

  k_cvt<<<(SEQ * HID / 4 + 255) / 256, 256, 0, stream>>>(hs, XB, SEQ * HID / 4);
  k_transpose_cvt<<<dim3(QKVN / 32, HID / 32), dim3(32, 8), 0, stream>>>(wqkv, WQKVT, HID, QKVN);
  // GEMM1: 192 blocks = 8 XCD x (3 bcol x 8 brow)
  k_gemm<1, 1, 3, 8><<<192, 512, 0, stream>>>(XB, WQKVT, QKV, nullptr, SEQ, QKVN, HID);
  k_transpose_cvt<<<dim3(HID / 32, HID / 32), dim3(32, 8), 0, stream>>>(wo, WOT, HID, HID);
  k_rmsrope<<<dim3(SEQ, 10), 256, 0, stream>>>(QKV, cosp, sinp, qw, kw, QR, KR);
  k_vt<<<dim3(SEQ / 32, HD / 32, NKVH), dim3(32, 8), 0, stream>>>(QKV, VTB);
  k_attn<<<512, 512, 0, stream>>>(QR, KR, VTB, AOB);
  // GEMM2: 256 blocks = 8 XCD x (2 bcol x 8 brow x 2 kz), split-K=2
  k_gemm<0, 2, 2, 8><<<256, 512, 0, stream>>>(AOB, WOT, out, SCR, SEQ, HID, HID);
  k_addf<<<SEQ * HID / 4 / 256, 256, 0, stream>>>(SCR, out, SEQ * HID / 4);
}